// Round 3
// baseline (145.674 us; speedup 1.0000x reference)
//
#include <hip/hip_runtime.h>
#include <stdint.h>

#define XC 4096      // CB*BS
#define MT 256       // batch rows per workgroup
#define NNZ 13       // nnz blocks per row block (setup guarantees)

typedef __attribute__((ext_vector_type(8))) short short8;
typedef __attribute__((ext_vector_type(4))) float f32x4;

static __device__ __forceinline__ unsigned short f2bf(float f) {
    union { float f; unsigned int u; } c; c.f = f;
    unsigned int u = c.u;
    unsigned int r = 0x7FFFu + ((u >> 16) & 1u);
    return (unsigned short)((u + r) >> 16);
}
static __device__ __forceinline__ unsigned int pk2(float a, float b) {   // round-nearest
    return (unsigned int)f2bf(a) | ((unsigned int)f2bf(b) << 16);
}
// one-instruction bf16x2 pack by truncation: low short = trunc(e), high = trunc(o)
static __device__ __forceinline__ unsigned int pktr(float e, float o) {
    return __builtin_amdgcn_perm(__float_as_uint(o), __float_as_uint(e), 0x07060302u);
}

// ---- prep: w*mask -> bf16 (RN), written in MFMA B-fragment order ----
// dest short idx = n*1024 + (o>>4)*512 + (s>>3)*128 + (o&15)*8 + (s&7)
__global__ void prep_w(const float* __restrict__ w, const float* __restrict__ m,
                       unsigned short* __restrict__ out, int nf4) {
    int i = blockIdx.x * 256 + threadIdx.x;
    if (i >= nf4) return;
    float4 a = ((const float4*)w)[i];
    float4 b = ((const float4*)m)[i];
    unsigned int lo = pk2(a.x * b.x, a.y * b.y);
    unsigned int hi = pk2(a.z * b.z, a.w * b.w);
    int e = i * 4;
    int n = e >> 10, rem = e & 1023;
    int o = rem >> 5, s = rem & 31;
    int dest = n * 1024 + ((o >> 4) << 9) + ((s >> 3) << 7) + ((o & 15) << 3) + (s & 7);
    *(uint2*)(out + dest) = make_uint2(lo, hi);
}

// ---- main: zero-LDS, zero-barrier register pipeline ----
// grid = 8 mt * 128 r (bx&127=r so consecutive blocks share the mt x-slice in L2).
// Wave owns 64 batch rows (4 mi tiles of 16). A-frags gathered fp32->perm-trunc bf16;
// B-frags are coalesced dwordx4 from fragment-ordered wbf.
__global__ __launch_bounds__(256, 4) void bsl_reg(
    const float* __restrict__ x, const int* __restrict__ cols,
    const unsigned short* __restrict__ wbf, const float* __restrict__ bias,
    float* __restrict__ out)
{
    const int bx   = blockIdx.x;
    const int r    = bx & 127;
    const int mt   = bx >> 7;
    const int row0 = mt * MT;

    const int lane = threadIdx.x & 63;
    const int wv   = threadIdx.x >> 6;
    const int l15  = lane & 15;
    const int quad = lane >> 4;

    int cseq[NNZ];
    #pragma unroll
    for (int nn = 0; nn < NNZ; ++nn)
        cseq[nn] = __builtin_amdgcn_readfirstlane(cols[r * NNZ + nn]);

    // per-lane x element offsets (floats) for the 4 mi tiles
    const int row0w = row0 + wv * 64;
    int voff[4];
    #pragma unroll
    for (int mi = 0; mi < 4; ++mi)
        voff[mi] = (row0w + mi * 16 + l15) * XC + quad * 8;

    // B-frag pointer: lane reads 16B at (r,nn,half,quad,l15) in frag order
    const unsigned short* wb = wbf + (size_t)r * (NNZ * 1024) + (quad << 7) + (l15 << 3);

    f32x4 acc[4][2];
    #pragma unroll
    for (int i = 0; i < 4; ++i)
        #pragma unroll
        for (int j = 0; j < 2; ++j)
            acc[i][j] = (f32x4){0.f, 0.f, 0.f, 0.f};

    // pipeline state: fp32 x buffer (single), bf16 B double-buffer
    float4 xv[4][2];
    short8 bfr[2][2];
    {
        const float* xc = x + cseq[0] * 32;
        #pragma unroll
        for (int mi = 0; mi < 4; ++mi) {
            xv[mi][0] = *(const float4*)(xc + voff[mi]);
            xv[mi][1] = *(const float4*)(xc + voff[mi] + 4);
        }
        bfr[0][0] = *(const short8*)(wb);
        bfr[0][1] = *(const short8*)(wb + 512);
    }

    #pragma unroll
    for (int nn = 0; nn < NNZ; ++nn) {
        const int cur = nn & 1, nxt = cur ^ 1;

        // prefetch next B-frags (independent regs; issues before the x waitcnt)
        if (nn + 1 < NNZ) {
            bfr[nxt][0] = *(const short8*)(wb + (nn + 1) * 1024);
            bfr[nxt][1] = *(const short8*)(wb + (nn + 1) * 1024 + 512);
        }

        // convert current chunk: 2 v_perm per 4 floats (truncation pack)
        union { short8 s; unsigned int u[4]; } afr[4];
        #pragma unroll
        for (int mi = 0; mi < 4; ++mi) {
            const float4 lo = xv[mi][0], hi = xv[mi][1];
            afr[mi].u[0] = pktr(lo.x, lo.y);
            afr[mi].u[1] = pktr(lo.z, lo.w);
            afr[mi].u[2] = pktr(hi.x, hi.y);
            afr[mi].u[3] = pktr(hi.z, hi.w);
        }

        // prefetch next chunk's x into the (now consumed) fp32 buffer
        if (nn + 1 < NNZ) {
            const float* xc = x + cseq[nn + 1] * 32;
            #pragma unroll
            for (int mi = 0; mi < 4; ++mi) {
                xv[mi][0] = *(const float4*)(xc + voff[mi]);
                xv[mi][1] = *(const float4*)(xc + voff[mi] + 4);
            }
        }

        #pragma unroll
        for (int mi = 0; mi < 4; ++mi) {
            acc[mi][0] = __builtin_amdgcn_mfma_f32_16x16x32_bf16(afr[mi].s, bfr[cur][0], acc[mi][0], 0, 0, 0);
            acc[mi][1] = __builtin_amdgcn_mfma_f32_16x16x32_bf16(afr[mi].s, bfr[cur][1], acc[mi][1], 0, 0, 0);
        }
    }

    // epilogue: C/D layout col=l15(=o), row=quad*4+reg(=m)
    const float b0v = bias[r * 32 + l15];
    const float b1v = bias[r * 32 + 16 + l15];
    #pragma unroll
    for (int mi = 0; mi < 4; ++mi) {
        const int rbase = row0 + wv * 64 + mi * 16 + quad * 4;
        #pragma unroll
        for (int reg = 0; reg < 4; ++reg) {
            float* op = out + (size_t)(rbase + reg) * XC + r * 32;
            op[l15]      = acc[mi][0][reg] + b0v;
            op[16 + l15] = acc[mi][1][reg] + b1v;
        }
    }
}

// ---- fallback (unexpected shape / tiny ws): barriered LDS version ----
__global__ __launch_bounds__(256, 3) void bsl_fallback(
    const float* __restrict__ x, const int* __restrict__ crow,
    const int* __restrict__ cols, const float* __restrict__ wf,
    const float* __restrict__ mf, const float* __restrict__ bias,
    float* __restrict__ out)
{
    __shared__ unsigned short w_lds[NNZ][32][40];
    __shared__ unsigned short x_lds[MT][40];

    const int tid = threadIdx.x;
    const int bx  = blockIdx.x;
    const int r   = bx & 127;
    const int mt  = bx >> 7;
    const int row0 = mt * MT;
    const int start = crow[r];
    const int nnzr  = crow[r + 1] - start;

    const float4* wsrc = (const float4*)(wf + (size_t)start * 1024);
    const float4* msrc = (const float4*)(mf + (size_t)start * 1024);
    for (int i = tid; i < nnzr * 256; i += 256) {
        int nn = i >> 8, rem = i & 255;
        int o = rem >> 3, sg = rem & 7;
        float4 a = wsrc[i], b = msrc[i];
        *(uint2*)&w_lds[nn][o][sg * 4] =
            make_uint2(pk2(a.x * b.x, a.y * b.y), pk2(a.z * b.z, a.w * b.w));
    }

    const int lane = tid & 63;
    const int wv   = tid >> 6;
    const int l15  = lane & 15;
    const int quad = lane >> 4;

    f32x4 acc[4][2];
    #pragma unroll
    for (int i = 0; i < 4; ++i)
        #pragma unroll
        for (int j = 0; j < 2; ++j)
            acc[i][j] = (f32x4){0.f, 0.f, 0.f, 0.f};

    const int s4 = tid & 7;
    const int rr = tid >> 3;
    float4 v[8];
    {
        int c = cols[start];
        const float* xb = x + (size_t)(row0 + rr) * XC + c * 32 + s4 * 4;
        #pragma unroll
        for (int j = 0; j < 8; ++j) v[j] = *(const float4*)(xb + (size_t)j * 32 * XC);
    }

    for (int nn = 0; nn < nnzr; ++nn) {
        __syncthreads();
        #pragma unroll
        for (int j = 0; j < 8; ++j)
            *(uint2*)&x_lds[rr + j * 32][s4 * 4] =
                make_uint2(pk2(v[j].x, v[j].y), pk2(v[j].z, v[j].w));
        __syncthreads();

        if (nn + 1 < nnzr) {
            int c = cols[start + nn + 1];
            const float* xb = x + (size_t)(row0 + rr) * XC + c * 32 + s4 * 4;
            #pragma unroll
            for (int j = 0; j < 8; ++j) v[j] = *(const float4*)(xb + (size_t)j * 32 * XC);
        }

        short8 b0 = *(const short8*)&w_lds[nn][l15][quad * 8];
        short8 b1 = *(const short8*)&w_lds[nn][16 + l15][quad * 8];
        #pragma unroll
        for (int mi = 0; mi < 4; ++mi) {
            short8 a = *(const short8*)&x_lds[wv * 64 + mi * 16 + l15][quad * 8];
            acc[mi][0] = __builtin_amdgcn_mfma_f32_16x16x32_bf16(a, b0, acc[mi][0], 0, 0, 0);
            acc[mi][1] = __builtin_amdgcn_mfma_f32_16x16x32_bf16(a, b1, acc[mi][1], 0, 0, 0);
        }
    }

    const float b0v = bias[r * 32 + l15];
    const float b1v = bias[r * 32 + 16 + l15];
    #pragma unroll
    for (int mi = 0; mi < 4; ++mi) {
        const int rbase = row0 + wv * 64 + mi * 16 + quad * 4;
        #pragma unroll
        for (int reg = 0; reg < 4; ++reg) {
            float* op = out + (size_t)(rbase + reg) * XC + r * 32;
            op[l15]      = acc[mi][0][reg] + b0v;
            op[16 + l15] = acc[mi][1][reg] + b1v;
        }
    }
}

extern "C" void kernel_launch(void* const* d_in, const int* in_sizes, int n_in,
                              void* d_out, int out_size, void* d_ws, size_t ws_size,
                              hipStream_t stream) {
    const float* x      = (const float*)d_in[0];
    const int*   crow   = (const int*)d_in[1];
    const int*   cols   = (const int*)d_in[2];
    const float* mask   = (const float*)d_in[3];
    const float* weight = (const float*)d_in[4];
    const float* bias   = (const float*)d_in[5];
    float* out = (float*)d_out;

    const int xel   = in_sizes[0];        // 2048*4096
    const int wel   = in_sizes[4];        // 1664*1024
    const int rb    = in_sizes[1] - 1;    // 128
    const int batch = xel / XC;           // 2048

    const size_t wb_bytes = (size_t)wel * 2;
    const bool fast = (ws_size >= wb_bytes) && (rb == 128) &&
                      (in_sizes[2] == rb * NNZ) && (batch % MT == 0);

    if (fast) {
        unsigned short* wbf = (unsigned short*)d_ws;
        int nw4 = wel / 4;
        prep_w<<<dim3((nw4 + 255) / 256), dim3(256), 0, stream>>>(weight, mask, wbf, nw4);
        bsl_reg<<<dim3(rb * (batch / MT)), dim3(256), 0, stream>>>(x, cols, wbf, bias, out);
    } else {
        bsl_fallback<<<dim3(rb * (batch / MT)), dim3(256), 0, stream>>>(
            x, crow, cols, weight, mask, bias, out);
    }
}